// Round 8
// baseline (444.247 us; speedup 1.0000x reference)
//
#include <hip/hip_runtime.h>
#include <hip/hip_bf16.h>

// KANLinear fused: LayerNorm -> {relu, cubic B-spline basis} -> single bf16 MFMA GEMM.
// N=32768 rows, F=512, U=512. K = F*8 = 4096 ([relu, b0..b5, 0] per feature).
// R9: back to the proven R0 2-phase structure, tuned for occupancy.
//  - 64x256 tile, 4 waves (wave 32x128, acc 2x8 = 64 AGPR), grid (2, 512).
//    44 KB LDS + __launch_bounds__(256,3) -> 3 blocks/CU: independent blocks
//    cover each other's barrier drains (m114). This was R0's missing lever.
//  - Single-barrier double-buffered loop (R3's proven loop body).
//  - A-gen map (row=tid>>2, feat=tid&3): x read = 16 lines/wave (was 64).
//  - gamma/beta staged in LDS (wave-broadcast reads).
//  - LN stats + Wt build merged into one prep dispatch.

#define N_ROWS 32768
#define F_DIM  512
#define U_DIM  512
#define K_DIM  4096

typedef short short8 __attribute__((ext_vector_type(8)));
typedef unsigned short ushort8v __attribute__((ext_vector_type(8)));
typedef float floatx4 __attribute__((ext_vector_type(4)));

__device__ __forceinline__ float bf2f(unsigned short h) {
    return __uint_as_float(((unsigned int)h) << 16);
}
__device__ __forceinline__ bool probe_bf16(const void* grid) {
    // fp32: grid[0] == -3.0f exactly (0xC0400000). bf16-packed: 0xC015C040.
    return ((const unsigned int*)grid)[0] != 0xC0400000u;
}
template <bool B16>
__device__ __forceinline__ float ldf(const void* p, int i) {
    return B16 ? bf2f(((const unsigned short*)p)[i]) : ((const float*)p)[i];
}
template <bool B16>
__device__ __forceinline__ void ld4v(const void* p, int i, float* o) {
    if (B16) {
        ushort4 v = *(const ushort4*)((const unsigned short*)p + i);
        o[0] = bf2f(v.x); o[1] = bf2f(v.y); o[2] = bf2f(v.z); o[3] = bf2f(v.w);
    } else {
        float4 v = *(const float4*)((const float*)p + i);
        o[0] = v.x; o[1] = v.y; o[2] = v.z; o[3] = v.w;
    }
}
__device__ __forceinline__ unsigned int pk2(float lo, float hi) {
    __hip_bfloat162 h = __float22bfloat162_rn(make_float2(lo, hi));
    return *reinterpret_cast<unsigned int*>(&h);
}
__device__ __forceinline__ void gld_lds16(const unsigned short* g, unsigned short* l) {
    __builtin_amdgcn_global_load_lds((const __attribute__((address_space(1))) void*)g,
                                     (__attribute__((address_space(3))) void*)l, 16, 0, 0);
}

// ---------------- prep: per-row LayerNorm stats + Wt[u][k] build ----------------
template <bool B16>
__device__ __forceinline__ void ln_stats_body(const void* __restrict__ x,
                                              float2* __restrict__ stats, int bid) {
    int wave = threadIdx.x >> 6, lane = threadIdx.x & 63;
    int row = bid * 4 + wave;
    float v[8];
    ld4v<B16>(x, row * F_DIM + lane * 8, v);
    ld4v<B16>(x, row * F_DIM + lane * 8 + 4, v + 4);
    float s = 0.f, s2 = 0.f;
#pragma unroll
    for (int k = 0; k < 8; ++k) { s += v[k]; s2 += v[k] * v[k]; }
#pragma unroll
    for (int off = 32; off > 0; off >>= 1) {
        s  += __shfl_xor(s, off);
        s2 += __shfl_xor(s2, off);
    }
    if (lane == 0) {
        float mean = s * (1.0f / F_DIM);
        float var  = s2 * (1.0f / F_DIM) - mean * mean;
        stats[row] = make_float2(mean, rsqrtf(var + 1e-3f));
    }
}
template <bool B16>
__device__ __forceinline__ void build_wt_body(const void* __restrict__ bw,
                                              const void* __restrict__ sw,
                                              unsigned short* __restrict__ wt, int bid) {
    int idx = bid * 256 + threadIdx.x;  // 0 .. 512*128
    int u = idx & 511;
    int fq = idx >> 9;  // 0..127 -> features fq*4 .. fq*4+3
#pragma unroll
    for (int i = 0; i < 4; ++i) {
        int f = fq * 4 + i;
        uint4 w;
        w.x = pk2(ldf<B16>(bw, f * U_DIM + u),            ldf<B16>(sw, (f * 6 + 0) * U_DIM + u));
        w.y = pk2(ldf<B16>(sw, (f * 6 + 1) * U_DIM + u),  ldf<B16>(sw, (f * 6 + 2) * U_DIM + u));
        w.z = pk2(ldf<B16>(sw, (f * 6 + 3) * U_DIM + u),  ldf<B16>(sw, (f * 6 + 4) * U_DIM + u));
        w.w = pk2(ldf<B16>(sw, (f * 6 + 5) * U_DIM + u),  0.f);
        *(uint4*)(wt + (size_t)u * K_DIM + f * 8) = w;
    }
}
__global__ __launch_bounds__(256) void prep_k(const void* __restrict__ x,
                                              const void* __restrict__ bw,
                                              const void* __restrict__ sw,
                                              const void* __restrict__ grid,
                                              float2* __restrict__ stats,
                                              unsigned short* __restrict__ wt) {
    int bid = blockIdx.x;
    if (probe_bf16(grid)) {
        if (bid < N_ROWS / 4) ln_stats_body<true>(x, stats, bid);
        else                  build_wt_body<true>(bw, sw, wt, bid - N_ROWS / 4);
    } else {
        if (bid < N_ROWS / 4) ln_stats_body<false>(x, stats, bid);
        else                  build_wt_body<false>(bw, sw, wt, bid - N_ROWS / 4);
    }
}

// ---------------- spline A-element: [relu, b0..b5, 0] -> 16B ----------------
__device__ __forceinline__ uint4 spline_pack(float xv, float gv, float bv,
                                             float mean, float rstd) {
    float xn = fmaf(xv - mean, rstd * gv, bv);
    float tt = fmaf(xn, 1.5f, 4.5f);  // t = (xn+3)/h, h=2/3
    float bb[6];
#pragma unroll
    for (int j = 0; j < 6; ++j) {
        float d = tt - (float)(j + 2);
        float a = fabsf(d);
        float a2 = d * d;
        float v1 = fmaf(fmaf(0.5f, a, -1.0f), a2, 0.66666669f);
        float c = fmaxf(2.0f - a, 0.0f);  // clamps a>=2 to 0 via cube
        float v2 = c * c * c * (1.0f / 6.0f);
        bb[j] = (a < 1.0f) ? v1 : v2;
    }
    uint4 o;
    o.x = pk2(fmaxf(xn, 0.f), bb[0]);
    o.y = pk2(bb[1], bb[2]);
    o.z = pk2(bb[3], bb[4]);
    o.w = pk2(bb[5], 0.f);
    return o;
}

// ---------------- fused GEMM ----------------
// 64 rows x 256 cols per block, BK=32, 4 waves (wr=wv>>1 row-group, wc=wv&1
// col-group), each wave 32x128 (acc 2x8 frags of 16x16x32). grid (2 ctiles,
// 512 rtiles); __launch_bounds__(256,3) + 44 KB LDS -> 3 blocks/CU.
// LDS slot layout (16B slots): A region: slot(r,q) = ((r>>4)*4+q)*16 + (r&15)
// (region = 64 rows x 4 feats = 4 KB); B: slot(cf,l) = cf*64 + l (col =
// cf*16 + (l&15), kchunk = l>>4) -> all frag reads lane-sequential 1KB
// ds_read_b128, conflict-free. B staged via source-permuted global_load_lds.
// A-gen: thread (row ar = tid>>2, feat-slot fg = tid&3) -> one spline/step;
// x read = 4 lanes per 64B line (16 lines/wave-instr).
// Loop: single barrier per K-step, A/B double-buffered (R3's proven body).
template <bool B16>
__device__ __forceinline__ void kan_gemm_body(
    const void* __restrict__ x,
    const float2* __restrict__ stats,
    const unsigned short* __restrict__ wt,
    const void* __restrict__ gam,
    const void* __restrict__ bet,
    const void* __restrict__ bias,
    void* __restrict__ out,
    unsigned short* __restrict__ Alds,   // 2 x 2048 shorts (4 KB each)
    unsigned short* __restrict__ Blds,   // 2 x 8192 shorts (16 KB each)
    float2* __restrict__ gb) {           // 512 (gamma, beta)

    const int tid = threadIdx.x;               // 0..255
    const int lane = tid & 63, wv = tid >> 6;  // wv 0..3
    const int ctile = blockIdx.x;              // 0..1
    const int rtile = blockIdx.y;              // 0..511
    const int lr = lane & 15, lq = lane >> 4;
    const int wr = wv >> 1, wc = wv & 1;

    // ---- gamma/beta -> LDS ----
    gb[tid]       = make_float2(ldf<B16>(gam, tid),       ldf<B16>(bet, tid));
    gb[tid + 256] = make_float2(ldf<B16>(gam, tid + 256), ldf<B16>(bet, tid + 256));

    // ---- A-gen setup: thread owns (row ar, feature-slot fg) ----
    const int ar = tid >> 2, fg = tid & 3;
    const int grow = rtile * 64 + ar;
    const float2 st = stats[grow];
    const float mean = st.x, rstd = st.y;
    const int xrow = grow * F_DIM;
    const int aoff = (((ar >> 4) * 4 + fg) * 16 + (ar & 15)) * 8;  // shorts

    // ---- B staging sources (slot s = wv*256 + i*64 + lane -> col C, kchunk q) ----
    const unsigned short* gsrc[4];
#pragma unroll
    for (int i = 0; i < 4; ++i) {
        int s = wv * 256 + i * 64 + lane;
        int C = ((s >> 6) << 4) | (s & 15);
        int q = (s >> 4) & 3;
        gsrc[i] = wt + (size_t)(ctile * 256 + C) * K_DIM + q * 8;
    }

    // ---- prologue: stage step 0 (B into buf0, A gen into buf0) ----
#pragma unroll
    for (int i = 0; i < 4; ++i)
        gld_lds16(gsrc[i], &Blds[(wv * 256 + i * 64) * 8]);
    {
        float xv = ldf<B16>(x, xrow + fg);
        // gb not yet synced; read gamma/beta direct from global once
        float gv = ldf<B16>(gam, fg), bv = ldf<B16>(bet, fg);
        *(uint4*)&Alds[aoff] = spline_pack(xv, gv, bv, mean, rstd);
    }
    __syncthreads();

    floatx4 acc[2][8];
#pragma unroll
    for (int mi = 0; mi < 2; ++mi)
#pragma unroll
        for (int ni = 0; ni < 8; ++ni) acc[mi][ni] = (floatx4){0.f, 0.f, 0.f, 0.f};

    // ---- main loop: compute step ks from buf[ks&1], stage ks+1 into other ----
    for (int ks = 0; ks < K_DIM / 32 - 1; ++ks) {
        const int cur = ks & 1, nxt = cur ^ 1;
        const unsigned short* __restrict__ Ac = Alds + cur * 2048;
        unsigned short* __restrict__ An = Alds + nxt * 2048;
        const unsigned short* __restrict__ Bc = Blds + cur * 8192;
        unsigned short* __restrict__ Bn = Blds + nxt * 8192;

        // stage B(ks+1) (4 x 16B per thread, wave-uniform dest base)
#pragma unroll
        for (int i = 0; i < 4; ++i)
            gld_lds16(gsrc[i] + (ks + 1) * 32, &Bn[(wv * 256 + i * 64) * 8]);

        // fragments of step ks (lane-sequential, conflict-free)
        short8 afr[2], bfr[8];
#pragma unroll
        for (int mi = 0; mi < 2; ++mi)
            afr[mi] = *(const short8*)&Ac[((wr * 2 + mi) * 64 + lane) * 8];
#pragma unroll
        for (int ni = 0; ni < 8; ++ni)
            bfr[ni] = *(const short8*)&Bc[((wc * 8 + ni) * 64 + lane) * 8];

        // gen A(ks+1): one feature per thread (x read: 16 lines/wave)
        {
            float xv = ldf<B16>(x, xrow + (ks + 1) * 4 + fg);
            float2 g2 = gb[(ks + 1) * 4 + fg];
            *(uint4*)&An[aoff] = spline_pack(xv, g2.x, g2.y, mean, rstd);
        }

        __builtin_amdgcn_s_setprio(1);
#pragma unroll
        for (int mi = 0; mi < 2; ++mi)
#pragma unroll
            for (int ni = 0; ni < 8; ++ni)
                acc[mi][ni] = __builtin_amdgcn_mfma_f32_16x16x32_bf16(
                    afr[mi], bfr[ni], acc[mi][ni], 0, 0, 0);
        __builtin_amdgcn_s_setprio(0);
        __syncthreads();  // nxt buffers ready; cur free to overwrite
    }

    // ---- final step (buffer 1), no staging ----
    {
        const unsigned short* Ac = Alds + 2048;
        const unsigned short* Bc = Blds + 8192;
        short8 afr[2], bfr[8];
#pragma unroll
        for (int mi = 0; mi < 2; ++mi)
            afr[mi] = *(const short8*)&Ac[((wr * 2 + mi) * 64 + lane) * 8];
#pragma unroll
        for (int ni = 0; ni < 8; ++ni)
            bfr[ni] = *(const short8*)&Bc[((wc * 8 + ni) * 64 + lane) * 8];
#pragma unroll
        for (int mi = 0; mi < 2; ++mi)
#pragma unroll
            for (int ni = 0; ni < 8; ++ni)
                acc[mi][ni] = __builtin_amdgcn_mfma_f32_16x16x32_bf16(
                    afr[mi], bfr[ni], acc[mi][ni], 0, 0, 0);
    }

    // ---- epilogue: + bias, store ----
    float biasv[8];
#pragma unroll
    for (int ni = 0; ni < 8; ++ni)
        biasv[ni] = ldf<B16>(bias, ctile * 256 + wc * 128 + ni * 16 + lr);
#pragma unroll
    for (int mi = 0; mi < 2; ++mi)
#pragma unroll
        for (int ni = 0; ni < 8; ++ni)
#pragma unroll
            for (int r = 0; r < 4; ++r) {
                int row = rtile * 64 + wr * 32 + mi * 16 + lq * 4 + r;
                int col = ctile * 256 + wc * 128 + ni * 16 + lr;
                float val = acc[mi][ni][r] + biasv[ni];
                if (B16) ((unsigned short*)out)[(size_t)row * U_DIM + col] =
                    (unsigned short)(pk2(val, 0.f) & 0xffffu);
                else ((float*)out)[(size_t)row * U_DIM + col] = val;
            }
}
__global__ __launch_bounds__(256, 3) void kan_gemm(
    const void* __restrict__ x, const float2* __restrict__ stats,
    const unsigned short* __restrict__ wt, const void* __restrict__ gam,
    const void* __restrict__ bet, const void* __restrict__ bias,
    const void* __restrict__ grid, void* __restrict__ out) {
    // LDS declared ONCE so <true>/<false> instantiations share it:
    // A 2x4 KB + B 2x16 KB + gb 4 KB = 44 KB -> 3 blocks/CU (132 <= 160 KB).
    __shared__ __align__(16) unsigned short Alds[2 * 2048];
    __shared__ __align__(16) unsigned short Blds[2 * 8192];
    __shared__ __align__(16) float2 gb_lds[512];
    if (probe_bf16(grid))
        kan_gemm_body<true>(x, stats, wt, gam, bet, bias, out, Alds, Blds, gb_lds);
    else
        kan_gemm_body<false>(x, stats, wt, gam, bet, bias, out, Alds, Blds, gb_lds);
}

extern "C" void kernel_launch(void* const* d_in, const int* in_sizes, int n_in,
                              void* d_out, int out_size, void* d_ws, size_t ws_size,
                              hipStream_t stream) {
    const void* x    = d_in[0];
    const void* gam  = d_in[1];
    const void* bet  = d_in[2];
    const void* bw   = d_in[3];
    const void* bb   = d_in[4];
    const void* sw   = d_in[5];
    const void* grid = d_in[6];  // uniform knots; also the dtype probe

    float2* stats = (float2*)d_ws;                                                  // 256 KB
    unsigned short* wt = (unsigned short*)((char*)d_ws + N_ROWS * sizeof(float2));  // 4 MB bf16

    hipLaunchKernelGGL(prep_k, dim3(N_ROWS / 4 + U_DIM * 128 / 256), dim3(256), 0, stream,
                       x, bw, sw, grid, stats, wt);
    hipLaunchKernelGGL(kan_gemm, dim3(2, N_ROWS / 64), dim3(256), 0, stream,
                       x, stats, wt, gam, bet, bb, grid, d_out);
}